// Round 3
// baseline (352.704 us; speedup 1.0000x reference)
//
#include <hip/hip_runtime.h>

// Problem constants (fp32 RQ-VAE nearest-codebook step)
#define Bn 8192
#define Kn 8192
#define Dn 512

typedef _Float16 half8 __attribute__((ext_vector_type(8)));
typedef _Float16 half4_t __attribute__((ext_vector_type(4)));
typedef float floatx16 __attribute__((ext_vector_type(16)));
typedef unsigned long long u64;

// Order-preserving map float -> u32 (monotone under unsigned compare, finite inputs)
__device__ __forceinline__ unsigned int fkey(float f) {
    unsigned int u = __float_as_uint(f);
    return (u & 0x80000000u) ? ~u : (u | 0x80000000u);
}

// async global->LDS, 16B per lane (global_load_lds_dwordx4)
__device__ __forceinline__ void gld16(const _Float16* g, _Float16* l) {
    __builtin_amdgcn_global_load_lds(
        (const __attribute__((address_space(1))) unsigned int*)g,
        (__attribute__((address_space(3))) unsigned int*)l, 16, 0, 0);
}

// ---------------- kernel: fp32 -> (hi,lo) f16 Dekker split, + e_sq fused ----------------
// blocks [0,4096) convert X; [4096,8192) convert E and also emit e_sq rows.
// Each block covers 1024 elements = 2 rows of 512.
__global__ __launch_bounds__(256) void convert_esq(
    const float* __restrict__ X, const float* __restrict__ E,
    _Float16* __restrict__ Xh, _Float16* __restrict__ Xl,
    _Float16* __restrict__ Eh, _Float16* __restrict__ El,
    float* __restrict__ esq)
{
    __shared__ float ws[4];
    const bool isE = blockIdx.x >= 4096;
    const int blk = blockIdx.x & 4095;
    const size_t base = ((size_t)blk * 256 + threadIdx.x) * 4;
    const float4 v = *(const float4*)((isE ? E : X) + base);
    half4_t h, l;
    h[0] = (_Float16)v.x; l[0] = (_Float16)(v.x - (float)h[0]);
    h[1] = (_Float16)v.y; l[1] = (_Float16)(v.y - (float)h[1]);
    h[2] = (_Float16)v.z; l[2] = (_Float16)(v.z - (float)h[2]);
    h[3] = (_Float16)v.w; l[3] = (_Float16)(v.w - (float)h[3]);
    *(half4_t*)((isE ? Eh : Xh) + base) = h;
    *(half4_t*)((isE ? El : Xl) + base) = l;
    if (isE) {
        // rows 2*blk (threads 0..127, waves 0-1) and 2*blk+1 (threads 128..255)
        float s = v.x*v.x + v.y*v.y + v.z*v.z + v.w*v.w;
        #pragma unroll
        for (int off = 32; off > 0; off >>= 1) s += __shfl_down(s, off, 64);
        if ((threadIdx.x & 63) == 0) ws[threadIdx.x >> 6] = s;
        __syncthreads();
        if (threadIdx.x == 0)  esq[2 * blk]     = ws[0] + ws[1];
        if (threadIdx.x == 64) esq[2 * blk + 1] = ws[2] + ws[3];
    }
}

// ---------------- kernel: 32x32x16 MFMA cross-term + fused argmin ----------------
// dist(b,k) = e_sq[k] - 2*(xh.eh + xh.el + xl.eh)
// 128x128 block tile; 4 waves of 64x64 (2x2 of 32x32x16 f16 MFMA).
// LDS holds tiles in MFMA-fragment order so every ds_read is lane-contiguous:
//   slot16B(row,k) = (row>>5)*128 + (k>>4)*64 + ((k>>3)&1)*32 + (row&31)
__global__ __launch_bounds__(256, 3) void argmin_mfma(
    const _Float16* __restrict__ Xh, const _Float16* __restrict__ Xl,
    const _Float16* __restrict__ Eh, const _Float16* __restrict__ El,
    const float* __restrict__ esq, u64* __restrict__ best)
{
    __shared__ __align__(16) _Float16 sXh[4096];
    __shared__ __align__(16) _Float16 sXl[4096];
    __shared__ __align__(16) _Float16 sEh[4096];
    __shared__ __align__(16) _Float16 sEl[4096];
    __shared__ u64 red[128][2];

    const int tid  = threadIdx.x;
    const int mb   = blockIdx.x >> 6;
    const int nb   = blockIdx.x & 63;
    const int m0   = mb * 128, n0 = nb * 128;
    const int lane = tid & 63, wave = tid >> 6;
    const int wx   = wave & 1, wy = wave >> 1;
    const int l31  = lane & 31, lhi = lane >> 5;

    floatx16 acc[2][2];
    #pragma unroll
    for (int i = 0; i < 2; ++i)
        #pragma unroll
        for (int j = 0; j < 2; ++j)
            #pragma unroll
            for (int r = 0; r < 16; ++r) acc[i][j][r] = 0.f;

    // staging: thread t fills slot t and slot t+256 (16B each); invert slot map
    const int trow = ((tid >> 7) << 5) + (tid & 31);               // [0,64)
    const int tcol = ((tid >> 6) & 1) * 16 + ((tid >> 5) & 1) * 8; // k offset
    const _Float16* gXh = Xh + (size_t)(m0 + trow) * Dn + tcol;
    const _Float16* gXl = Xl + (size_t)(m0 + trow) * Dn + tcol;
    const _Float16* gEh = Eh + (size_t)(n0 + trow) * Dn + tcol;
    const _Float16* gEl = El + (size_t)(n0 + trow) * Dn + tcol;
    const size_t rstep = (size_t)64 * Dn;      // rows 64..127 -> slots 256..511
    _Float16* dXh = &sXh[tid * 8]; _Float16* dXl = &sXl[tid * 8];
    _Float16* dEh = &sEh[tid * 8]; _Float16* dEl = &sEl[tid * 8];

    // fragment read bases (halfs): slot*8 with slot=(wy*2+mi)*128 + ks*64 + lane
    const int aoff = (wy * 2) * 1024 + lane * 8;
    const int boff = (wx * 2) * 1024 + lane * 8;

    for (int d0 = 0; d0 < Dn; d0 += 32) {
        __syncthreads();                       // prev chunk's LDS reads done
        gld16(gXh + d0,         dXh);
        gld16(gXh + rstep + d0, dXh + 2048);
        gld16(gXl + d0,         dXl);
        gld16(gXl + rstep + d0, dXl + 2048);
        gld16(gEh + d0,         dEh);
        gld16(gEh + rstep + d0, dEh + 2048);
        gld16(gEl + d0,         dEl);
        gld16(gEl + rstep + d0, dEl + 2048);
        __syncthreads();                       // drains vmcnt -> data visible

        #pragma unroll
        for (int ks = 0; ks < 2; ++ks) {
            const int ko = ks * 512;
            half8 ah0 = *(const half8*)&sXh[aoff + ko];
            half8 ah1 = *(const half8*)&sXh[aoff + 1024 + ko];
            half8 al0 = *(const half8*)&sXl[aoff + ko];
            half8 al1 = *(const half8*)&sXl[aoff + 1024 + ko];
            half8 bh0 = *(const half8*)&sEh[boff + ko];
            half8 bh1 = *(const half8*)&sEh[boff + 1024 + ko];
            half8 bl0 = *(const half8*)&sEl[boff + ko];
            half8 bl1 = *(const half8*)&sEl[boff + 1024 + ko];

            acc[0][0] = __builtin_amdgcn_mfma_f32_32x32x16_f16(ah0, bh0, acc[0][0], 0, 0, 0);
            acc[0][1] = __builtin_amdgcn_mfma_f32_32x32x16_f16(ah0, bh1, acc[0][1], 0, 0, 0);
            acc[1][0] = __builtin_amdgcn_mfma_f32_32x32x16_f16(ah1, bh0, acc[1][0], 0, 0, 0);
            acc[1][1] = __builtin_amdgcn_mfma_f32_32x32x16_f16(ah1, bh1, acc[1][1], 0, 0, 0);

            acc[0][0] = __builtin_amdgcn_mfma_f32_32x32x16_f16(ah0, bl0, acc[0][0], 0, 0, 0);
            acc[0][1] = __builtin_amdgcn_mfma_f32_32x32x16_f16(ah0, bl1, acc[0][1], 0, 0, 0);
            acc[1][0] = __builtin_amdgcn_mfma_f32_32x32x16_f16(ah1, bl0, acc[1][0], 0, 0, 0);
            acc[1][1] = __builtin_amdgcn_mfma_f32_32x32x16_f16(ah1, bl1, acc[1][1], 0, 0, 0);

            acc[0][0] = __builtin_amdgcn_mfma_f32_32x32x16_f16(al0, bh0, acc[0][0], 0, 0, 0);
            acc[0][1] = __builtin_amdgcn_mfma_f32_32x32x16_f16(al0, bh1, acc[0][1], 0, 0, 0);
            acc[1][0] = __builtin_amdgcn_mfma_f32_32x32x16_f16(al1, bh0, acc[1][0], 0, 0, 0);
            acc[1][1] = __builtin_amdgcn_mfma_f32_32x32x16_f16(al1, bh1, acc[1][1], 0, 0, 0);
        }
    }

    // epilogue: dist = esq - 2*cross; 32x32 C/D layout (m74/m101):
    //   col = lane&31, row = (reg&3) + 8*(reg>>2) + 4*(lane>>5)
    const int   c0  = n0 + wx * 64 + l31;
    const float eq0 = esq[c0];
    const float eq1 = esq[c0 + 32];
    #pragma unroll
    for (int mi = 0; mi < 2; ++mi) {
        #pragma unroll
        for (int r = 0; r < 16; ++r) {
            float dv0 = eq0 - 2.0f * acc[mi][0][r];
            float dv1 = eq1 - 2.0f * acc[mi][1][r];
            u64 k0 = ((u64)fkey(dv0) << 32) | (u64)(unsigned int)c0;
            u64 k1 = ((u64)fkey(dv1) << 32) | (u64)(unsigned int)(c0 + 32);
            u64 key = (k1 < k0) ? k1 : k0;
            #pragma unroll
            for (int off = 1; off < 32; off <<= 1) {   // stays within 32-lane half
                u64 o = __shfl_xor(key, off);
                if (o < key) key = o;
            }
            if (l31 == 0) {
                int row = wy * 64 + mi * 32 + (r & 3) + ((r >> 2) << 3) + (lhi << 2);
                red[row][wx] = key;
            }
        }
    }
    __syncthreads();
    if (tid < 128) {
        u64 a = red[tid][0], b = red[tid][1];
        best[(size_t)(m0 + tid) * 64 + nb] = (b < a) ? b : a;
    }
}

// ---------------- fallback (round-1 fp32 path, used only if ws too small) ----------------
#define KSPLIT 16
#define LDSW 132
__global__ __launch_bounds__(256) void esq_kernel(const float* __restrict__ E,
                                                  float* __restrict__ esq) {
    int wave = threadIdx.x >> 6;
    int lane = threadIdx.x & 63;
    int k = blockIdx.x * 4 + wave;
    const float4* row = (const float4*)(E + (size_t)k * Dn);
    float4 v0 = row[lane];
    float4 v1 = row[64 + lane];
    float s = v0.x*v0.x + v0.y*v0.y + v0.z*v0.z + v0.w*v0.w
            + v1.x*v1.x + v1.y*v1.y + v1.z*v1.z + v1.w*v1.w;
    #pragma unroll
    for (int off = 32; off > 0; off >>= 1) s += __shfl_down(s, off, 64);
    if (lane == 0) esq[k] = s;
}

__global__ __launch_bounds__(256, 2) void argmin_fp32(
    const float* __restrict__ X, const float* __restrict__ E,
    const float* __restrict__ esq, u64* __restrict__ best)
{
    __shared__ __align__(16) float Xs[16][LDSW];
    __shared__ __align__(16) float Es[16][LDSW];
    __shared__ u64 red[128][16];
    const int tid = threadIdx.x;
    const int tx = tid & 15, ty = tid >> 4;
    const int rowTile = blockIdx.x / KSPLIT;
    const int split   = blockIdx.x % KSPLIT;
    const int m0 = rowTile * 128;
    const int kbase = split * (Kn / KSPLIT);
    float bestv[8]; int besti[8];
    #pragma unroll
    for (int i = 0; i < 8; ++i) { bestv[i] = INFINITY; besti[i] = 0; }
    const int ldRow = tid >> 2, ldD = (tid & 3) * 4;
    for (int kt = 0; kt < (Kn / KSPLIT) / 128; ++kt) {
        const int k0 = kbase + kt * 128;
        float acc[8][8] = {};
        for (int dc = 0; dc < Dn / 16; ++dc) {
            const int d0 = dc * 16;
            float4 xa = *(const float4*)&X[(size_t)(m0 + ldRow)      * Dn + d0 + ldD];
            float4 xb = *(const float4*)&X[(size_t)(m0 + 64 + ldRow) * Dn + d0 + ldD];
            float4 ea = *(const float4*)&E[(size_t)(k0 + ldRow)      * Dn + d0 + ldD];
            float4 eb = *(const float4*)&E[(size_t)(k0 + 64 + ldRow) * Dn + d0 + ldD];
            __syncthreads();
            Xs[ldD+0][ldRow] = xa.x; Xs[ldD+1][ldRow] = xa.y;
            Xs[ldD+2][ldRow] = xa.z; Xs[ldD+3][ldRow] = xa.w;
            Xs[ldD+0][64+ldRow] = xb.x; Xs[ldD+1][64+ldRow] = xb.y;
            Xs[ldD+2][64+ldRow] = xb.z; Xs[ldD+3][64+ldRow] = xb.w;
            Es[ldD+0][ldRow] = ea.x; Es[ldD+1][ldRow] = ea.y;
            Es[ldD+2][ldRow] = ea.z; Es[ldD+3][ldRow] = ea.w;
            Es[ldD+0][64+ldRow] = eb.x; Es[ldD+1][64+ldRow] = eb.y;
            Es[ldD+2][64+ldRow] = eb.z; Es[ldD+3][64+ldRow] = eb.w;
            __syncthreads();
            #pragma unroll
            for (int d = 0; d < 16; ++d) {
                float a8[8], b8[8];
                *(float4*)&a8[0] = *(const float4*)&Xs[d][4*ty];
                *(float4*)&a8[4] = *(const float4*)&Xs[d][64 + 4*ty];
                *(float4*)&b8[0] = *(const float4*)&Es[d][4*tx];
                *(float4*)&b8[4] = *(const float4*)&Es[d][64 + 4*tx];
                #pragma unroll
                for (int i = 0; i < 8; ++i)
                    #pragma unroll
                    for (int j = 0; j < 8; ++j) acc[i][j] += a8[i] * b8[j];
            }
        }
        #pragma unroll
        for (int j = 0; j < 8; ++j) {
            const int c = k0 + ((j < 4) ? (4*tx + j) : (64 + 4*tx + (j - 4)));
            const float eq = esq[c];
            #pragma unroll
            for (int i = 0; i < 8; ++i) {
                float dval = eq - 2.0f * acc[i][j];
                if (dval < bestv[i]) { bestv[i] = dval; besti[i] = c; }
            }
        }
    }
    #pragma unroll
    for (int i = 0; i < 8; ++i) {
        int rloc = (i < 4) ? (4*ty + i) : (64 + 4*ty + (i - 4));
        red[rloc][tx] = ((u64)fkey(bestv[i]) << 32) | (u64)(unsigned int)besti[i];
    }
    __syncthreads();
    if (tid < 128) {
        u64 m = red[tid][0];
        #pragma unroll
        for (int t = 1; t < 16; ++t) { u64 v = red[tid][t]; if (v < m) m = v; }
        best[(size_t)(m0 + tid) * KSPLIT + split] = m;
    }
}

// ---------------- kernel: reduce splits, write index + residual ----------------
__global__ __launch_bounds__(128) void finalize_kernel(
    const float* __restrict__ X, const float* __restrict__ E,
    const u64* __restrict__ best, float* __restrict__ out, int nsplits)
{
    __shared__ int sidx;
    const int b = blockIdx.x, t = threadIdx.x;
    if (t < 64) {
        u64 v = (t < nsplits) ? best[(size_t)b * nsplits + t] : ~0ull;
        #pragma unroll
        for (int off = 1; off < 64; off <<= 1) {
            u64 o = __shfl_xor(v, off);
            if (o < v) v = o;
        }
        if (t == 0) {
            int idx = (int)(unsigned int)(v & 0xFFFFFFFFull);
            sidx = idx;
            out[b] = (float)idx;
        }
    }
    __syncthreads();
    const int idx = sidx;
    float4 x = ((const float4*)(X + (size_t)b * Dn))[t];
    float4 e = ((const float4*)(E + (size_t)idx * Dn))[t];
    float4 r; r.x = x.x - e.x; r.y = x.y - e.y; r.z = x.z - e.z; r.w = x.w - e.w;
    ((float4*)(out + Bn + (size_t)b * Dn))[t] = r;
}

extern "C" void kernel_launch(void* const* d_in, const int* in_sizes, int n_in,
                              void* d_out, int out_size, void* d_ws, size_t ws_size,
                              hipStream_t stream) {
    const float* X = (const float*)d_in[0];   // previous_residual [B, D]
    const float* E = (const float*)d_in[1];   // codebook_embeddings [K, D]
    float* out = (float*)d_out;               // [B] idx-as-float ++ [B*D] residual

    // fast-path ws layout: esq (32KB) | Xh | Xl | Eh | El (8MB each) | best (4MB)
    const size_t HB = (size_t)Bn * Dn * sizeof(_Float16);   // 8 MB
    const size_t NEED = 32768 + 4 * HB + (size_t)Bn * 64 * sizeof(u64);

    float* esq = (float*)d_ws;

    if (ws_size >= NEED) {
        _Float16* Xh = (_Float16*)((char*)d_ws + 32768);
        _Float16* Xl = (_Float16*)((char*)d_ws + 32768 + HB);
        _Float16* Eh = (_Float16*)((char*)d_ws + 32768 + 2 * HB);
        _Float16* El = (_Float16*)((char*)d_ws + 32768 + 3 * HB);
        u64* best    = (u64*)((char*)d_ws + 32768 + 4 * HB);
        convert_esq<<<8192, 256, 0, stream>>>(X, E, Xh, Xl, Eh, El, esq);
        argmin_mfma<<<64 * 64, 256, 0, stream>>>(Xh, Xl, Eh, El, esq, best);
        finalize_kernel<<<Bn, 128, 0, stream>>>(X, E, best, out, 64);
    } else {
        u64* best = (u64*)((char*)d_ws + 32768);
        esq_kernel<<<Kn / 4, 256, 0, stream>>>(E, esq);
        argmin_fp32<<<(Bn / 128) * KSPLIT, 256, 0, stream>>>(X, E, esq, best);
        finalize_kernel<<<Bn, 128, 0, stream>>>(X, E, best, out, KSPLIT);
    }
}

// Round 4
// 332.805 us; speedup vs baseline: 1.0598x; 1.0598x over previous
//
#include <hip/hip_runtime.h>

// Problem constants (fp32 RQ-VAE nearest-codebook step)
#define Bn 8192
#define Kn 8192
#define Dn 512

typedef _Float16 half8 __attribute__((ext_vector_type(8)));
typedef _Float16 half4_t __attribute__((ext_vector_type(4)));
typedef float floatx4 __attribute__((ext_vector_type(4)));
typedef unsigned long long u64;

// Order-preserving map float -> u32 (monotone under unsigned compare, finite inputs)
__device__ __forceinline__ unsigned int fkey(float f) {
    unsigned int u = __float_as_uint(f);
    return (u & 0x80000000u) ? ~u : (u | 0x80000000u);
}

// async global->LDS, 16B per lane (global_load_lds_dwordx4)
__device__ __forceinline__ void gld16(const _Float16* g, _Float16* l) {
    __builtin_amdgcn_global_load_lds(
        (const __attribute__((address_space(1))) unsigned int*)g,
        (__attribute__((address_space(3))) unsigned int*)l, 16, 0, 0);
}

// ---------------- kernel: fp32 -> (hi,lo) f16 Dekker split, + e_sq fused ----------------
// blocks [0,4096) convert X; [4096,8192) convert E and also emit e_sq rows.
__global__ __launch_bounds__(256) void convert_esq(
    const float* __restrict__ X, const float* __restrict__ E,
    _Float16* __restrict__ Xh, _Float16* __restrict__ Xl,
    _Float16* __restrict__ Eh, _Float16* __restrict__ El,
    float* __restrict__ esq)
{
    __shared__ float ws[4];
    const bool isE = blockIdx.x >= 4096;
    const int blk = blockIdx.x & 4095;
    const size_t base = ((size_t)blk * 256 + threadIdx.x) * 4;
    const float4 v = *(const float4*)((isE ? E : X) + base);
    half4_t h, l;
    h[0] = (_Float16)v.x; l[0] = (_Float16)(v.x - (float)h[0]);
    h[1] = (_Float16)v.y; l[1] = (_Float16)(v.y - (float)h[1]);
    h[2] = (_Float16)v.z; l[2] = (_Float16)(v.z - (float)h[2]);
    h[3] = (_Float16)v.w; l[3] = (_Float16)(v.w - (float)h[3]);
    *(half4_t*)((isE ? Eh : Xh) + base) = h;
    *(half4_t*)((isE ? El : Xl) + base) = l;
    if (isE) {
        float s = v.x*v.x + v.y*v.y + v.z*v.z + v.w*v.w;
        #pragma unroll
        for (int off = 32; off > 0; off >>= 1) s += __shfl_down(s, off, 64);
        if ((threadIdx.x & 63) == 0) ws[threadIdx.x >> 6] = s;
        __syncthreads();
        if (threadIdx.x == 0)  esq[2 * blk]     = ws[0] + ws[1];
        if (threadIdx.x == 64) esq[2 * blk + 1] = ws[2] + ws[3];
    }
}

// ---------------- kernel: MFMA cross-term + fused argmin ----------------
// dist(b,k) = e_sq[k] - 2*(xh.eh + xh.el + xl.eh);  128x128 block tile,
// 4 waves of 64x64 (4x4 of 16x16x32 f16 MFMA).
// LDS holds tiles in MFMA-fragment order -> every ds_read_b128 lane-contiguous:
//   slot16B(row,kq) = (row>>4)*64 + kq*16 + (row&15),  kq = k>>3 in [0,4)
// Fragment read base for (grp=row>>4): (grp*64 + lane) * 16B  (zero conflicts).
// Staging inverse: thread t -> row ((t>>6)<<4)+(t&15), kcol ((t>>4)&3)*8
//   (wave = 16 rows x 64B contiguous global segments).
__global__ __launch_bounds__(256, 3) void argmin_mfma(
    const _Float16* __restrict__ Xh, const _Float16* __restrict__ Xl,
    const _Float16* __restrict__ Eh, const _Float16* __restrict__ El,
    const float* __restrict__ esq, u64* __restrict__ best)
{
    __shared__ __align__(16) _Float16 sXh[4096];
    __shared__ __align__(16) _Float16 sXl[4096];
    __shared__ __align__(16) _Float16 sEh[4096];
    __shared__ __align__(16) _Float16 sEl[4096];
    __shared__ u64 red[128][2];

    const int tid  = threadIdx.x;
    const int mb   = blockIdx.x >> 6;      // 64 m-blocks
    const int nb   = blockIdx.x & 63;      // 64 n-blocks
    const int m0   = mb * 128, n0 = nb * 128;
    const int lane = tid & 63, wave = tid >> 6;
    const int wx   = wave & 1, wy = wave >> 1;   // wave tile origin (wy*64, wx*64)
    const int colg = lane & 15, quad = lane >> 4;

    floatx4 acc[4][4];
    #pragma unroll
    for (int i = 0; i < 4; ++i)
        #pragma unroll
        for (int j = 0; j < 4; ++j) acc[i][j] = {0.f, 0.f, 0.f, 0.f};

    // staging map (inverse of fragment-order slots)
    const int trow = ((tid >> 6) << 4) + (tid & 15);   // [0,64)
    const int tcol = ((tid >> 4) & 3) * 8;             // k offset in halves
    const _Float16* gXh = Xh + (size_t)(m0 + trow) * Dn + tcol;
    const _Float16* gXl = Xl + (size_t)(m0 + trow) * Dn + tcol;
    const _Float16* gEh = Eh + (size_t)(n0 + trow) * Dn + tcol;
    const _Float16* gEl = El + (size_t)(n0 + trow) * Dn + tcol;
    const size_t rstep = (size_t)64 * Dn;              // rows 64..127 -> slots 256..511
    _Float16* dXh = &sXh[tid * 8]; _Float16* dXl = &sXl[tid * 8];
    _Float16* dEh = &sEh[tid * 8]; _Float16* dEl = &sEl[tid * 8];

    const int abase = (wy * 4) * 512 + lane * 8;   // + mi*512
    const int bbase = (wx * 4) * 512 + lane * 8;   // + ni*512

    for (int d0 = 0; d0 < Dn; d0 += 32) {
        __syncthreads();                       // prev chunk's LDS reads done
        gld16(gXh + d0,         dXh);
        gld16(gXh + rstep + d0, dXh + 2048);
        gld16(gXl + d0,         dXl);
        gld16(gXl + rstep + d0, dXl + 2048);
        gld16(gEh + d0,         dEh);
        gld16(gEh + rstep + d0, dEh + 2048);
        gld16(gEl + d0,         dEl);
        gld16(gEl + rstep + d0, dEl + 2048);
        __syncthreads();                       // drains vmcnt -> data visible

        half8 bh[4], bl[4];
        #pragma unroll
        for (int ni = 0; ni < 4; ++ni) {
            bh[ni] = *(const half8*)&sEh[bbase + ni * 512];
            bl[ni] = *(const half8*)&sEl[bbase + ni * 512];
        }
        #pragma unroll
        for (int mi = 0; mi < 4; ++mi) {
            half8 ah = *(const half8*)&sXh[abase + mi * 512];
            half8 al = *(const half8*)&sXl[abase + mi * 512];
            #pragma unroll
            for (int ni = 0; ni < 4; ++ni) {
                acc[mi][ni] = __builtin_amdgcn_mfma_f32_16x16x32_f16(ah, bh[ni], acc[mi][ni], 0, 0, 0);
                acc[mi][ni] = __builtin_amdgcn_mfma_f32_16x16x32_f16(ah, bl[ni], acc[mi][ni], 0, 0, 0);
                acc[mi][ni] = __builtin_amdgcn_mfma_f32_16x16x32_f16(al, bh[ni], acc[mi][ni], 0, 0, 0);
            }
        }
    }

    // epilogue: dist = esq - 2*cross, per-row argmin over this block's 128 cols.
    // C/D layout: col = lane&15, row = quad*4 + reg  (m89-verified)
    #pragma unroll
    for (int mi = 0; mi < 4; ++mi) {
        #pragma unroll
        for (int r = 0; r < 4; ++r) {
            float bv = INFINITY; int bi = 0;
            #pragma unroll
            for (int ni = 0; ni < 4; ++ni) {   // ascending col -> '<' keeps low idx
                int c = wx * 64 + ni * 16 + colg;
                float dv = esq[n0 + c] - 2.0f * acc[mi][ni][r];
                if (dv < bv) { bv = dv; bi = n0 + c; }
            }
            u64 key = ((u64)fkey(bv) << 32) | (u64)(unsigned int)bi;
            #pragma unroll
            for (int off = 1; off < 16; off <<= 1) {
                u64 o = __shfl_xor(key, off);
                if (o < key) key = o;
            }
            if (colg == 0) red[wy * 64 + mi * 16 + quad * 4 + r][wx] = key;
        }
    }
    __syncthreads();
    if (tid < 128) {
        u64 a = red[tid][0], b = red[tid][1];
        best[(size_t)(m0 + tid) * 64 + nb] = (b < a) ? b : a;
    }
}

// ---------------- fallback (round-1 fp32 path, used only if ws too small) ----------------
#define KSPLIT 16
#define LDSW 132
__global__ __launch_bounds__(256) void esq_kernel(const float* __restrict__ E,
                                                  float* __restrict__ esq) {
    int wave = threadIdx.x >> 6;
    int lane = threadIdx.x & 63;
    int k = blockIdx.x * 4 + wave;
    const float4* row = (const float4*)(E + (size_t)k * Dn);
    float4 v0 = row[lane];
    float4 v1 = row[64 + lane];
    float s = v0.x*v0.x + v0.y*v0.y + v0.z*v0.z + v0.w*v0.w
            + v1.x*v1.x + v1.y*v1.y + v1.z*v1.z + v1.w*v1.w;
    #pragma unroll
    for (int off = 32; off > 0; off >>= 1) s += __shfl_down(s, off, 64);
    if (lane == 0) esq[k] = s;
}

__global__ __launch_bounds__(256, 2) void argmin_fp32(
    const float* __restrict__ X, const float* __restrict__ E,
    const float* __restrict__ esq, u64* __restrict__ best)
{
    __shared__ __align__(16) float Xs[16][LDSW];
    __shared__ __align__(16) float Es[16][LDSW];
    __shared__ u64 red[128][16];
    const int tid = threadIdx.x;
    const int tx = tid & 15, ty = tid >> 4;
    const int rowTile = blockIdx.x / KSPLIT;
    const int split   = blockIdx.x % KSPLIT;
    const int m0 = rowTile * 128;
    const int kbase = split * (Kn / KSPLIT);
    float bestv[8]; int besti[8];
    #pragma unroll
    for (int i = 0; i < 8; ++i) { bestv[i] = INFINITY; besti[i] = 0; }
    const int ldRow = tid >> 2, ldD = (tid & 3) * 4;
    for (int kt = 0; kt < (Kn / KSPLIT) / 128; ++kt) {
        const int k0 = kbase + kt * 128;
        float acc[8][8] = {};
        for (int dc = 0; dc < Dn / 16; ++dc) {
            const int d0 = dc * 16;
            float4 xa = *(const float4*)&X[(size_t)(m0 + ldRow)      * Dn + d0 + ldD];
            float4 xb = *(const float4*)&X[(size_t)(m0 + 64 + ldRow) * Dn + d0 + ldD];
            float4 ea = *(const float4*)&E[(size_t)(k0 + ldRow)      * Dn + d0 + ldD];
            float4 eb = *(const float4*)&E[(size_t)(k0 + 64 + ldRow) * Dn + d0 + ldD];
            __syncthreads();
            Xs[ldD+0][ldRow] = xa.x; Xs[ldD+1][ldRow] = xa.y;
            Xs[ldD+2][ldRow] = xa.z; Xs[ldD+3][ldRow] = xa.w;
            Xs[ldD+0][64+ldRow] = xb.x; Xs[ldD+1][64+ldRow] = xb.y;
            Xs[ldD+2][64+ldRow] = xb.z; Xs[ldD+3][64+ldRow] = xb.w;
            Es[ldD+0][ldRow] = ea.x; Es[ldD+1][ldRow] = ea.y;
            Es[ldD+2][ldRow] = ea.z; Es[ldD+3][ldRow] = ea.w;
            Es[ldD+0][64+ldRow] = eb.x; Es[ldD+1][64+ldRow] = eb.y;
            Es[ldD+2][64+ldRow] = eb.z; Es[ldD+3][64+ldRow] = eb.w;
            __syncthreads();
            #pragma unroll
            for (int d = 0; d < 16; ++d) {
                float a8[8], b8[8];
                *(float4*)&a8[0] = *(const float4*)&Xs[d][4*ty];
                *(float4*)&a8[4] = *(const float4*)&Xs[d][64 + 4*ty];
                *(float4*)&b8[0] = *(const float4*)&Es[d][4*tx];
                *(float4*)&b8[4] = *(const float4*)&Es[d][64 + 4*tx];
                #pragma unroll
                for (int i = 0; i < 8; ++i)
                    #pragma unroll
                    for (int j = 0; j < 8; ++j) acc[i][j] += a8[i] * b8[j];
            }
        }
        #pragma unroll
        for (int j = 0; j < 8; ++j) {
            const int c = k0 + ((j < 4) ? (4*tx + j) : (64 + 4*tx + (j - 4)));
            const float eq = esq[c];
            #pragma unroll
            for (int i = 0; i < 8; ++i) {
                float dval = eq - 2.0f * acc[i][j];
                if (dval < bestv[i]) { bestv[i] = dval; besti[i] = c; }
            }
        }
    }
    #pragma unroll
    for (int i = 0; i < 8; ++i) {
        int rloc = (i < 4) ? (4*ty + i) : (64 + 4*ty + (i - 4));
        red[rloc][tx] = ((u64)fkey(bestv[i]) << 32) | (u64)(unsigned int)besti[i];
    }
    __syncthreads();
    if (tid < 128) {
        u64 m = red[tid][0];
        #pragma unroll
        for (int t = 1; t < 16; ++t) { u64 v = red[tid][t]; if (v < m) m = v; }
        best[(size_t)(m0 + tid) * KSPLIT + split] = m;
    }
}

// ---------------- kernel: reduce splits, write index + residual ----------------
// 2 rows per block: threads [0,128) -> row 2b, [128,256) -> row 2b+1.
__global__ __launch_bounds__(256) void finalize_kernel(
    const float* __restrict__ X, const float* __restrict__ E,
    const u64* __restrict__ best, float* __restrict__ out, int nsplits)
{
    __shared__ int sidx[2];
    const int half = threadIdx.x >> 7;          // 0 or 1
    const int t    = threadIdx.x & 127;
    const int b    = blockIdx.x * 2 + half;
    if (t < 64) {
        u64 v = (t < nsplits) ? best[(size_t)b * nsplits + t] : ~0ull;
        #pragma unroll
        for (int off = 1; off < 64; off <<= 1) {
            u64 o = __shfl_xor(v, off);
            if (o < v) v = o;
        }
        if (t == 0) {
            int idx = (int)(unsigned int)(v & 0xFFFFFFFFull);
            sidx[half] = idx;
            out[b] = (float)idx;
        }
    }
    __syncthreads();
    const int idx = sidx[half];
    float4 x = ((const float4*)(X + (size_t)b * Dn))[t];
    float4 e = ((const float4*)(E + (size_t)idx * Dn))[t];
    float4 r; r.x = x.x - e.x; r.y = x.y - e.y; r.z = x.z - e.z; r.w = x.w - e.w;
    ((float4*)(out + Bn + (size_t)b * Dn))[t] = r;
}

extern "C" void kernel_launch(void* const* d_in, const int* in_sizes, int n_in,
                              void* d_out, int out_size, void* d_ws, size_t ws_size,
                              hipStream_t stream) {
    const float* X = (const float*)d_in[0];   // previous_residual [B, D]
    const float* E = (const float*)d_in[1];   // codebook_embeddings [K, D]
    float* out = (float*)d_out;               // [B] idx-as-float ++ [B*D] residual

    // fast-path ws layout: esq (32KB) | Xh | Xl | Eh | El (8MB each) | best (4MB)
    const size_t HB = (size_t)Bn * Dn * sizeof(_Float16);   // 8 MB
    const size_t NEED = 32768 + 4 * HB + (size_t)Bn * 64 * sizeof(u64);

    float* esq = (float*)d_ws;

    if (ws_size >= NEED) {
        _Float16* Xh = (_Float16*)((char*)d_ws + 32768);
        _Float16* Xl = (_Float16*)((char*)d_ws + 32768 + HB);
        _Float16* Eh = (_Float16*)((char*)d_ws + 32768 + 2 * HB);
        _Float16* El = (_Float16*)((char*)d_ws + 32768 + 3 * HB);
        u64* best    = (u64*)((char*)d_ws + 32768 + 4 * HB);
        convert_esq<<<8192, 256, 0, stream>>>(X, E, Xh, Xl, Eh, El, esq);
        argmin_mfma<<<64 * 64, 256, 0, stream>>>(Xh, Xl, Eh, El, esq, best);
        finalize_kernel<<<Bn / 2, 256, 0, stream>>>(X, E, best, out, 64);
    } else {
        u64* best = (u64*)((char*)d_ws + 32768);
        esq_kernel<<<Kn / 4, 256, 0, stream>>>(E, esq);
        argmin_fp32<<<(Bn / 128) * KSPLIT, 256, 0, stream>>>(X, E, esq, best);
        finalize_kernel<<<Bn / 2, 256, 0, stream>>>(X, E, best, out, KSPLIT);
    }
}

// Round 5
// 271.326 us; speedup vs baseline: 1.2999x; 1.2266x over previous
//
#include <hip/hip_runtime.h>

// Problem constants (fp32 RQ-VAE nearest-codebook step)
#define Bn 8192
#define Kn 8192
#define Dn 512

typedef _Float16 half8 __attribute__((ext_vector_type(8)));
typedef _Float16 half4_t __attribute__((ext_vector_type(4)));
typedef float floatx4 __attribute__((ext_vector_type(4)));
typedef unsigned long long u64;

// Order-preserving map float -> u32 (monotone under unsigned compare, finite inputs)
__device__ __forceinline__ unsigned int fkey(float f) {
    unsigned int u = __float_as_uint(f);
    return (u & 0x80000000u) ? ~u : (u | 0x80000000u);
}

// async global->LDS, 16B per lane (global_load_lds_dwordx4)
__device__ __forceinline__ void gld16(const _Float16* g, _Float16* l) {
    __builtin_amdgcn_global_load_lds(
        (const __attribute__((address_space(1))) unsigned int*)g,
        (__attribute__((address_space(3))) unsigned int*)l, 16, 0, 0);
}

// ---------------- kernel: e_sq[k] = ||E[k]||^2 ----------------
__global__ __launch_bounds__(256) void esq_kernel(const float* __restrict__ E,
                                                  float* __restrict__ esq) {
    int wave = threadIdx.x >> 6;
    int lane = threadIdx.x & 63;
    int k = blockIdx.x * 4 + wave;
    const float4* row = (const float4*)(E + (size_t)k * Dn);
    float4 v0 = row[lane];
    float4 v1 = row[64 + lane];
    float s = v0.x*v0.x + v0.y*v0.y + v0.z*v0.z + v0.w*v0.w
            + v1.x*v1.x + v1.y*v1.y + v1.z*v1.z + v1.w*v1.w;
    #pragma unroll
    for (int off = 32; off > 0; off >>= 1) s += __shfl_down(s, off, 64);
    if (lane == 0) esq[k] = s;
}

// ---------------- kernel: fp32 -> (hi,lo) f16 split, PACKED tile layout ------
// Output layout: G[panel][chunk][slot], panel = 128 rows, chunk = 32 k-halves,
//   slot(row128, kq) = (row128>>6)*256 + ((row128>>4)&3)*64 + kq*16 + (row128&15)
// so GEMM staging gld16(gbase + t*16B -> lds + t*16B) is wave-contiguous in
// global AND lands in MFMA-fragment order in LDS (zero read conflicts).
__global__ __launch_bounds__(256) void convert_packed(
    const float* __restrict__ src,
    _Float16* __restrict__ Gh, _Float16* __restrict__ Gl)
{
    const int panel = blockIdx.x >> 4;      // 64 panels of 128 rows
    const int chunk = blockIdx.x & 15;      // 16 chunks of 32 halves
    const int t = threadIdx.x;
    #pragma unroll
    for (int s0 = 0; s0 < 2; ++s0) {
        const int s = t + s0 * 256;                      // slot in [0,512)
        const int half64 = s >> 8, mi = (s >> 6) & 3;
        const int kq = (s >> 4) & 3, r = s & 15;
        const int row = panel * 128 + half64 * 64 + mi * 16 + r;
        const int k   = chunk * 32 + kq * 8;
        const float4 v0 = *(const float4*)&src[(size_t)row * Dn + k];
        const float4 v1 = *(const float4*)&src[(size_t)row * Dn + k + 4];
        half8 h, l;
        h[0]=(_Float16)v0.x; l[0]=(_Float16)(v0.x-(float)h[0]);
        h[1]=(_Float16)v0.y; l[1]=(_Float16)(v0.y-(float)h[1]);
        h[2]=(_Float16)v0.z; l[2]=(_Float16)(v0.z-(float)h[2]);
        h[3]=(_Float16)v0.w; l[3]=(_Float16)(v0.w-(float)h[3]);
        h[4]=(_Float16)v1.x; l[4]=(_Float16)(v1.x-(float)h[4]);
        h[5]=(_Float16)v1.y; l[5]=(_Float16)(v1.y-(float)h[5]);
        h[6]=(_Float16)v1.z; l[6]=(_Float16)(v1.z-(float)h[6]);
        h[7]=(_Float16)v1.w; l[7]=(_Float16)(v1.w-(float)h[7]);
        const size_t off = ((size_t)(panel * 16 + chunk) * 512 + s) * 8;
        *(half8*)&Gh[off] = h;
        *(half8*)&Gl[off] = l;
    }
}

// ---------------- kernel: MFMA cross-term + fused argmin ----------------
// dist(b,k) = e_sq[k] - 2*(xh.eh + xh.el + xl.eh);  128x128 block tile,
// 4 waves of 64x64 (4x4 of 16x16x32 f16 MFMA). Inputs pre-packed: staging is
// slot t -> lds slot t (contiguous both sides), reads are fragment-contiguous.
__global__ __launch_bounds__(256, 3) void argmin_mfma(
    const _Float16* __restrict__ Xh, const _Float16* __restrict__ Xl,
    const _Float16* __restrict__ Eh, const _Float16* __restrict__ El,
    const float* __restrict__ esq, u64* __restrict__ best)
{
    __shared__ __align__(16) _Float16 sXh[4096];
    __shared__ __align__(16) _Float16 sXl[4096];
    __shared__ __align__(16) _Float16 sEh[4096];
    __shared__ __align__(16) _Float16 sEl[4096];
    __shared__ u64 red[128][2];

    const int tid  = threadIdx.x;
    const int mb   = blockIdx.x >> 6;      // 64 m-blocks
    const int nb   = blockIdx.x & 63;      // 64 n-blocks
    const int m0   = mb * 128, n0 = nb * 128;
    const int lane = tid & 63, wave = tid >> 6;
    const int wx   = wave & 1, wy = wave >> 1;   // wave tile origin (wy*64, wx*64)
    const int colg = lane & 15, quad = lane >> 4;

    floatx4 acc[4][4];
    #pragma unroll
    for (int i = 0; i < 4; ++i)
        #pragma unroll
        for (int j = 0; j < 4; ++j) acc[i][j] = {0.f, 0.f, 0.f, 0.f};

    // packed panel base: panel stride = 16 chunks * 4096 halves
    const _Float16* gXh = Xh + (size_t)mb * 65536 + tid * 8;
    const _Float16* gXl = Xl + (size_t)mb * 65536 + tid * 8;
    const _Float16* gEh = Eh + (size_t)nb * 65536 + tid * 8;
    const _Float16* gEl = El + (size_t)nb * 65536 + tid * 8;
    _Float16* dXh = &sXh[tid * 8]; _Float16* dXl = &sXl[tid * 8];
    _Float16* dEh = &sEh[tid * 8]; _Float16* dEl = &sEl[tid * 8];

    // fragment read bases (halves): slot = wy*256 + mi*64 + lane
    const int aoff = wy * 2048 + lane * 8;   // + mi*512
    const int boff = wx * 2048 + lane * 8;   // + ni*512

    for (int c = 0; c < 16; ++c) {
        const size_t gb = (size_t)c * 4096;     // chunk stride in halves
        __syncthreads();                        // prev chunk's LDS reads done
        gld16(gXh + gb,        dXh);
        gld16(gXh + gb + 2048, dXh + 2048);
        gld16(gXl + gb,        dXl);
        gld16(gXl + gb + 2048, dXl + 2048);
        gld16(gEh + gb,        dEh);
        gld16(gEh + gb + 2048, dEh + 2048);
        gld16(gEl + gb,        dEl);
        gld16(gEl + gb + 2048, dEl + 2048);
        __syncthreads();                        // drains vmcnt -> data visible

        half8 bh[4], bl[4];
        #pragma unroll
        for (int ni = 0; ni < 4; ++ni) {
            bh[ni] = *(const half8*)&sEh[boff + ni * 512];
            bl[ni] = *(const half8*)&sEl[boff + ni * 512];
        }
        #pragma unroll
        for (int mi = 0; mi < 4; ++mi) {
            half8 ah = *(const half8*)&sXh[aoff + mi * 512];
            half8 al = *(const half8*)&sXl[aoff + mi * 512];
            #pragma unroll
            for (int ni = 0; ni < 4; ++ni) {
                acc[mi][ni] = __builtin_amdgcn_mfma_f32_16x16x32_f16(ah, bh[ni], acc[mi][ni], 0, 0, 0);
                acc[mi][ni] = __builtin_amdgcn_mfma_f32_16x16x32_f16(ah, bl[ni], acc[mi][ni], 0, 0, 0);
                acc[mi][ni] = __builtin_amdgcn_mfma_f32_16x16x32_f16(al, bh[ni], acc[mi][ni], 0, 0, 0);
            }
        }
    }

    // epilogue: dist = esq - 2*cross, per-row argmin over this block's 128 cols.
    // C/D layout: col = lane&15, row = quad*4 + reg  (m89-verified)
    #pragma unroll
    for (int mi = 0; mi < 4; ++mi) {
        #pragma unroll
        for (int r = 0; r < 4; ++r) {
            float bv = INFINITY; int bi = 0;
            #pragma unroll
            for (int ni = 0; ni < 4; ++ni) {   // ascending col -> '<' keeps low idx
                int c = wx * 64 + ni * 16 + colg;
                float dv = esq[n0 + c] - 2.0f * acc[mi][ni][r];
                if (dv < bv) { bv = dv; bi = n0 + c; }
            }
            u64 key = ((u64)fkey(bv) << 32) | (u64)(unsigned int)bi;
            #pragma unroll
            for (int off = 1; off < 16; off <<= 1) {
                u64 o = __shfl_xor(key, off);
                if (o < key) key = o;
            }
            if (colg == 0) red[wy * 64 + mi * 16 + quad * 4 + r][wx] = key;
        }
    }
    __syncthreads();
    if (tid < 128) {
        u64 a = red[tid][0], b = red[tid][1];
        best[(size_t)(m0 + tid) * 64 + nb] = (b < a) ? b : a;
    }
}

// ---------------- fallback (round-1 fp32 path, used only if ws too small) ----
#define KSPLIT 16
#define LDSW 132
__global__ __launch_bounds__(256, 2) void argmin_fp32(
    const float* __restrict__ X, const float* __restrict__ E,
    const float* __restrict__ esq, u64* __restrict__ best)
{
    __shared__ __align__(16) float Xs[16][LDSW];
    __shared__ __align__(16) float Es[16][LDSW];
    __shared__ u64 red[128][16];
    const int tid = threadIdx.x;
    const int tx = tid & 15, ty = tid >> 4;
    const int rowTile = blockIdx.x / KSPLIT;
    const int split   = blockIdx.x % KSPLIT;
    const int m0 = rowTile * 128;
    const int kbase = split * (Kn / KSPLIT);
    float bestv[8]; int besti[8];
    #pragma unroll
    for (int i = 0; i < 8; ++i) { bestv[i] = INFINITY; besti[i] = 0; }
    const int ldRow = tid >> 2, ldD = (tid & 3) * 4;
    for (int kt = 0; kt < (Kn / KSPLIT) / 128; ++kt) {
        const int k0 = kbase + kt * 128;
        float acc[8][8] = {};
        for (int dc = 0; dc < Dn / 16; ++dc) {
            const int d0 = dc * 16;
            float4 xa = *(const float4*)&X[(size_t)(m0 + ldRow)      * Dn + d0 + ldD];
            float4 xb = *(const float4*)&X[(size_t)(m0 + 64 + ldRow) * Dn + d0 + ldD];
            float4 ea = *(const float4*)&E[(size_t)(k0 + ldRow)      * Dn + d0 + ldD];
            float4 eb = *(const float4*)&E[(size_t)(k0 + 64 + ldRow) * Dn + d0 + ldD];
            __syncthreads();
            Xs[ldD+0][ldRow] = xa.x; Xs[ldD+1][ldRow] = xa.y;
            Xs[ldD+2][ldRow] = xa.z; Xs[ldD+3][ldRow] = xa.w;
            Xs[ldD+0][64+ldRow] = xb.x; Xs[ldD+1][64+ldRow] = xb.y;
            Xs[ldD+2][64+ldRow] = xb.z; Xs[ldD+3][64+ldRow] = xb.w;
            Es[ldD+0][ldRow] = ea.x; Es[ldD+1][ldRow] = ea.y;
            Es[ldD+2][ldRow] = ea.z; Es[ldD+3][ldRow] = ea.w;
            Es[ldD+0][64+ldRow] = eb.x; Es[ldD+1][64+ldRow] = eb.y;
            Es[ldD+2][64+ldRow] = eb.z; Es[ldD+3][64+ldRow] = eb.w;
            __syncthreads();
            #pragma unroll
            for (int d = 0; d < 16; ++d) {
                float a8[8], b8[8];
                *(float4*)&a8[0] = *(const float4*)&Xs[d][4*ty];
                *(float4*)&a8[4] = *(const float4*)&Xs[d][64 + 4*ty];
                *(float4*)&b8[0] = *(const float4*)&Es[d][4*tx];
                *(float4*)&b8[4] = *(const float4*)&Es[d][64 + 4*tx];
                #pragma unroll
                for (int i = 0; i < 8; ++i)
                    #pragma unroll
                    for (int j = 0; j < 8; ++j) acc[i][j] += a8[i] * b8[j];
            }
        }
        #pragma unroll
        for (int j = 0; j < 8; ++j) {
            const int c = k0 + ((j < 4) ? (4*tx + j) : (64 + 4*tx + (j - 4)));
            const float eq = esq[c];
            #pragma unroll
            for (int i = 0; i < 8; ++i) {
                float dval = eq - 2.0f * acc[i][j];
                if (dval < bestv[i]) { bestv[i] = dval; besti[i] = c; }
            }
        }
    }
    #pragma unroll
    for (int i = 0; i < 8; ++i) {
        int rloc = (i < 4) ? (4*ty + i) : (64 + 4*ty + (i - 4));
        red[rloc][tx] = ((u64)fkey(bestv[i]) << 32) | (u64)(unsigned int)besti[i];
    }
    __syncthreads();
    if (tid < 128) {
        u64 m = red[tid][0];
        #pragma unroll
        for (int t = 1; t < 16; ++t) { u64 v = red[tid][t]; if (v < m) m = v; }
        best[(size_t)(m0 + tid) * KSPLIT + split] = m;
    }
}

// ---------------- kernel: reduce splits, write index + residual ----------------
// 2 rows per block: threads [0,128) -> row 2b, [128,256) -> row 2b+1.
__global__ __launch_bounds__(256) void finalize_kernel(
    const float* __restrict__ X, const float* __restrict__ E,
    const u64* __restrict__ best, float* __restrict__ out, int nsplits)
{
    __shared__ int sidx[2];
    const int half = threadIdx.x >> 7;
    const int t    = threadIdx.x & 127;
    const int b    = blockIdx.x * 2 + half;
    if (t < 64) {
        u64 v = (t < nsplits) ? best[(size_t)b * nsplits + t] : ~0ull;
        #pragma unroll
        for (int off = 1; off < 64; off <<= 1) {
            u64 o = __shfl_xor(v, off);
            if (o < v) v = o;
        }
        if (t == 0) {
            int idx = (int)(unsigned int)(v & 0xFFFFFFFFull);
            sidx[half] = idx;
            out[b] = (float)idx;
        }
    }
    __syncthreads();
    const int idx = sidx[half];
    float4 x = ((const float4*)(X + (size_t)b * Dn))[t];
    float4 e = ((const float4*)(E + (size_t)idx * Dn))[t];
    float4 r; r.x = x.x - e.x; r.y = x.y - e.y; r.z = x.z - e.z; r.w = x.w - e.w;
    ((float4*)(out + Bn + (size_t)b * Dn))[t] = r;
}

extern "C" void kernel_launch(void* const* d_in, const int* in_sizes, int n_in,
                              void* d_out, int out_size, void* d_ws, size_t ws_size,
                              hipStream_t stream) {
    const float* X = (const float*)d_in[0];   // previous_residual [B, D]
    const float* E = (const float*)d_in[1];   // codebook_embeddings [K, D]
    float* out = (float*)d_out;               // [B] idx-as-float ++ [B*D] residual

    // fast-path ws layout: esq (32KB) | Xh | Xl | Eh | El (8MB each) | best (4MB)
    const size_t HB = (size_t)Bn * Dn * sizeof(_Float16);   // 8 MB
    const size_t NEED = 32768 + 4 * HB + (size_t)Bn * 64 * sizeof(u64);

    float* esq = (float*)d_ws;

    if (ws_size >= NEED) {
        _Float16* Xh = (_Float16*)((char*)d_ws + 32768);
        _Float16* Xl = (_Float16*)((char*)d_ws + 32768 + HB);
        _Float16* Eh = (_Float16*)((char*)d_ws + 32768 + 2 * HB);
        _Float16* El = (_Float16*)((char*)d_ws + 32768 + 3 * HB);
        u64* best    = (u64*)((char*)d_ws + 32768 + 4 * HB);
        esq_kernel<<<Kn / 4, 256, 0, stream>>>(E, esq);
        convert_packed<<<1024, 256, 0, stream>>>(X, Xh, Xl);
        convert_packed<<<1024, 256, 0, stream>>>(E, Eh, El);
        argmin_mfma<<<64 * 64, 256, 0, stream>>>(Xh, Xl, Eh, El, esq, best);
        finalize_kernel<<<Bn / 2, 256, 0, stream>>>(X, E, best, out, 64);
    } else {
        u64* best = (u64*)((char*)d_ws + 32768);
        esq_kernel<<<Kn / 4, 256, 0, stream>>>(E, esq);
        argmin_fp32<<<(Bn / 128) * KSPLIT, 256, 0, stream>>>(X, E, esq, best);
        finalize_kernel<<<Bn / 2, 256, 0, stream>>>(X, E, best, out, KSPLIT);
    }
}